// Round 1
// baseline (2262.464 us; speedup 1.0000x reference)
//
#include <hip/hip_runtime.h>
#include <hip/hip_bf16.h>
#include <math.h>

#define T_TOK 16384
#define H_DIM 1024
#define I_DIM 2048
#define E_NUM 16
#define MAX_TILES 272   // sum_e ceil(cnt_e/128) <= (32768 + 16*127)/128 < 272

typedef short bf16x8 __attribute__((ext_vector_type(8)));
typedef float f32x4 __attribute__((ext_vector_type(4)));

// ---------------- workspace layout (bytes) ----------------
static constexpr size_t XB_BYTES  = (size_t)T_TOK * H_DIM * 2;           // 32 MB
static constexpr size_t W_BYTES   = (size_t)E_NUM * H_DIM * I_DIM * 2;   // 64 MB
static constexpr size_t HB_BYTES  = (size_t)2 * T_TOK * I_DIM * 2;       // 128 MB
static constexpr size_t LIST_BYTES= (size_t)E_NUM * T_TOK * 4;           // 1 MB

static constexpr size_t XB_OFF    = 0;
static constexpr size_t WGT_OFF   = XB_OFF + XB_BYTES;
static constexpr size_t WUT_OFF   = WGT_OFF + W_BYTES;
static constexpr size_t WDT_OFF   = WUT_OFF + W_BYTES;
static constexpr size_t HB_OFF    = WDT_OFF + W_BYTES;
static constexpr size_t ROWS_OFF  = HB_OFF + HB_BYTES;
static constexpr size_t WTS_OFF   = ROWS_OFF + LIST_BYTES;
static constexpr size_t CNT_OFF   = WTS_OFF + LIST_BYTES;
static constexpr size_t BASE_OFF  = CNT_OFF + 256;
static constexpr size_t TILES_OFF = BASE_OFF + 256;
static constexpr size_t NT_OFF    = TILES_OFF + 2048;

// ---------------- fp32 -> bf16 straight convert (x) ----------------
__global__ void convert_x_kernel(const float* __restrict__ x, __hip_bfloat16* __restrict__ xb) {
    int i = (blockIdx.x * 256 + threadIdx.x) * 4;
    const float4 v = *(const float4*)(x + i);
    union { __hip_bfloat16 h[4]; ushort4 u; } cv;
    cv.h[0] = __float2bfloat16(v.x);
    cv.h[1] = __float2bfloat16(v.y);
    cv.h[2] = __float2bfloat16(v.z);
    cv.h[3] = __float2bfloat16(v.w);
    *(ushort4*)(xb + i) = cv.u;
}

// in: [E][R][C] fp32  ->  out: [E][C][R] bf16   (B^T layout for MFMA frag reads)
__global__ void transpose_convert_kernel(const float* __restrict__ in,
                                         __hip_bfloat16* __restrict__ out,
                                         int R, int C) {
    __shared__ float tile[32][33];
    int e = blockIdx.z;
    int c0 = blockIdx.x * 32;
    int r0 = blockIdx.y * 32;
    const float* pin = in + (size_t)e * R * C;
    __hip_bfloat16* pout = out + (size_t)e * R * C;
    int tx = threadIdx.x, ty = threadIdx.y;   // block (32,8)
    #pragma unroll
    for (int j = 0; j < 4; j++)
        tile[ty + j*8][tx] = pin[(size_t)(r0 + ty + j*8) * C + (c0 + tx)];
    __syncthreads();
    #pragma unroll
    for (int j = 0; j < 4; j++)
        pout[(size_t)(c0 + ty + j*8) * R + (r0 + tx)] = __float2bfloat16(tile[tx][ty + j*8]);
}

// ---------------- router: fp64 logits, top-2, renorm, atomic list build ----------------
__global__ void router_kernel(const float* __restrict__ x, const float* __restrict__ wg,
                              int* __restrict__ cnt, int* __restrict__ rows,
                              float* __restrict__ wts) {
    int t = blockIdx.x;
    int lane = threadIdx.x;   // 64 threads = 1 wave
    float xv[16];
    const float* xp = x + (size_t)t * H_DIM;
    #pragma unroll
    for (int j = 0; j < 16; j++) xv[j] = xp[j*64 + lane];
    double logits[E_NUM];
    #pragma unroll
    for (int e = 0; e < E_NUM; e++) {
        double p = 0.0;
        #pragma unroll
        for (int j = 0; j < 16; j++)
            p += (double)xv[j] * (double)wg[(j*64 + lane) * E_NUM + e];
        #pragma unroll
        for (int off = 32; off > 0; off >>= 1) p += __shfl_down(p, off);
        logits[e] = p;
    }
    if (lane == 0) {
        int i1 = 0; double v1 = logits[0];
        #pragma unroll
        for (int e = 1; e < E_NUM; e++) if (logits[e] > v1) { v1 = logits[e]; i1 = e; }
        int i2 = -1; double v2 = -1e300;
        #pragma unroll
        for (int e = 0; e < E_NUM; e++) if (e != i1 && logits[e] > v2) { v2 = logits[e]; i2 = e; }
        // renormalized top-2 softmax weights: w1 = p1/(p1+p2) = 1/(1+exp(l2-l1))
        double w1 = 1.0 / (1.0 + exp(v2 - v1));
        float w1f = (float)w1, w2f = (float)(1.0 - w1);
        int s1 = atomicAdd(&cnt[i1], 1);
        rows[i1 * T_TOK + s1] = t; wts[i1 * T_TOK + s1] = w1f;
        int s2 = atomicAdd(&cnt[i2], 1);
        rows[i2 * T_TOK + s2] = t; wts[i2 * T_TOK + s2] = w2f;
    }
}

// ---------------- schedule: exclusive scan + tile descriptors ----------------
__global__ void schedule_kernel(const int* __restrict__ cnt, int* __restrict__ base,
                                int* __restrict__ tiles, int* __restrict__ ntiles) {
    int b = 0, nt = 0;
    for (int e = 0; e < E_NUM; e++) {
        base[e] = b;
        int c = cnt[e];
        int m = (c + 127) >> 7;
        for (int i = 0; i < m; i++) tiles[nt++] = (e << 16) | i;
        b += c;
    }
    ntiles[0] = nt;
}

// ---------------- GEMM-C: fused gate+up+SiLU ----------------
// A = gathered x rows (bf16 [tok][H]); B = Wgt/Wut [E][I][H] (B^T layout)
// h[base_e + slot][i] = u * silu(g), bf16
__global__ __launch_bounds__(256) void gemm_gateup_kernel(
    const __hip_bfloat16* __restrict__ xb,
    const __hip_bfloat16* __restrict__ Wgt,
    const __hip_bfloat16* __restrict__ Wut,
    __hip_bfloat16* __restrict__ hbuf,
    const int* __restrict__ rows, const int* __restrict__ cnt,
    const int* __restrict__ base, const int* __restrict__ tiles,
    const int* __restrict__ ntiles)
{
    if ((int)blockIdx.y >= ntiles[0]) return;
    int td = tiles[blockIdx.y];
    int e = td >> 16, tile = td & 0xffff;
    int cnt_e = cnt[e];
    int base_e = base[e];
    int cnt_local = cnt_e - tile * 128;
    int bn = blockIdx.x;                       // N-tile over I (16 tiles of 128)
    const int* rows_e = rows + e * T_TOK;
    const __hip_bfloat16* Wg_e = Wgt + (size_t)e * I_DIM * H_DIM;
    const __hip_bfloat16* Wu_e = Wut + (size_t)e * I_DIM * H_DIM;

    __shared__ __align__(16) __hip_bfloat16 As [128][72];
    __shared__ __align__(16) __hip_bfloat16 Bgs[128][72];
    __shared__ __align__(16) __hip_bfloat16 Bus[128][72];

    int tid = threadIdx.x;
    int rb = tid >> 3;               // 0..31
    int c8 = (tid & 7) * 8;          // 0..56, 8-elem chunks

    int tok[4]; bool tv[4];
    #pragma unroll
    for (int i = 0; i < 4; i++) {
        int gr = tile*128 + rb + 32*i;
        tv[i] = gr < cnt_e;
        tok[i] = tv[i] ? rows_e[gr] : 0;
    }

    int lane = tid & 63, w = tid >> 6;
    int wm = w >> 1, wn = w & 1;
    int l16 = lane & 15, quad = lane >> 4;

    f32x4 accg[4][4], accu[4][4];
    #pragma unroll
    for (int a = 0; a < 4; a++)
        #pragma unroll
        for (int b = 0; b < 4; b++) {
            accg[a][b] = (f32x4){0.f, 0.f, 0.f, 0.f};
            accu[a][b] = (f32x4){0.f, 0.f, 0.f, 0.f};
        }

    const bf16x8 zero8 = {0,0,0,0,0,0,0,0};
    for (int k0 = 0; k0 < H_DIM; k0 += 64) {
        #pragma unroll
        for (int i = 0; i < 4; i++) {
            int r = rb + 32*i;
            bf16x8 av = zero8;
            if (tv[i]) av = *(const bf16x8*)(xb + (size_t)tok[i]*H_DIM + k0 + c8);
            *(bf16x8*)&As[r][c8] = av;
            int n = bn*128 + r;
            *(bf16x8*)&Bgs[r][c8] = *(const bf16x8*)(Wg_e + (size_t)n*H_DIM + k0 + c8);
            *(bf16x8*)&Bus[r][c8] = *(const bf16x8*)(Wu_e + (size_t)n*H_DIM + k0 + c8);
        }
        __syncthreads();
        #pragma unroll
        for (int ks = 0; ks < 2; ks++) {
            bf16x8 af[4], bg[4], bu[4];
            #pragma unroll
            for (int mt = 0; mt < 4; mt++)
                af[mt] = *(const bf16x8*)&As[wm*64 + mt*16 + l16][ks*32 + quad*8];
            #pragma unroll
            for (int nt = 0; nt < 4; nt++) {
                bg[nt] = *(const bf16x8*)&Bgs[wn*64 + nt*16 + l16][ks*32 + quad*8];
                bu[nt] = *(const bf16x8*)&Bus[wn*64 + nt*16 + l16][ks*32 + quad*8];
            }
            #pragma unroll
            for (int mt = 0; mt < 4; mt++)
                #pragma unroll
                for (int nt = 0; nt < 4; nt++) {
                    accg[mt][nt] = __builtin_amdgcn_mfma_f32_16x16x32_bf16(af[mt], bg[nt], accg[mt][nt], 0, 0, 0);
                    accu[mt][nt] = __builtin_amdgcn_mfma_f32_16x16x32_bf16(af[mt], bu[nt], accu[mt][nt], 0, 0, 0);
                }
        }
        __syncthreads();
    }

    #pragma unroll
    for (int mt = 0; mt < 4; mt++) {
        #pragma unroll
        for (int r = 0; r < 4; r++) {
            int row = wm*64 + mt*16 + quad*4 + r;
            if (row < cnt_local) {
                size_t hr = (size_t)(base_e + tile*128 + row) * I_DIM;
                #pragma unroll
                for (int nt = 0; nt < 4; nt++) {
                    int col = bn*128 + wn*64 + nt*16 + l16;
                    float g = accg[mt][nt][r];
                    float u = accu[mt][nt][r];
                    float hv = u * (g / (1.f + expf(-g)));
                    hbuf[hr + col] = __float2bfloat16(hv);
                }
            }
        }
    }
}

// ---------------- GEMM-D: down proj + weighted scatter ----------------
__global__ __launch_bounds__(256) void gemm_down_kernel(
    const __hip_bfloat16* __restrict__ hbuf,
    const __hip_bfloat16* __restrict__ Wdt,   // [E][H][I] (B^T layout)
    float* __restrict__ out,
    const int* __restrict__ rows, const float* __restrict__ wts,
    const int* __restrict__ cnt, const int* __restrict__ base,
    const int* __restrict__ tiles, const int* __restrict__ ntiles)
{
    if ((int)blockIdx.y >= ntiles[0]) return;
    int td = tiles[blockIdx.y];
    int e = td >> 16, tile = td & 0xffff;
    int cnt_e = cnt[e];
    int base_e = base[e];
    int cnt_local = cnt_e - tile * 128;
    int bn = blockIdx.x;                       // N-tile over H (8 tiles of 128)
    const int* rows_e = rows + e * T_TOK;
    const float* wts_e = wts + e * T_TOK;
    const __hip_bfloat16* Wd_e = Wdt + (size_t)e * H_DIM * I_DIM;

    __shared__ __align__(16) __hip_bfloat16 As[128][72];
    __shared__ __align__(16) __hip_bfloat16 Bs[128][72];

    int tid = threadIdx.x;
    int rb = tid >> 3;
    int c8 = (tid & 7) * 8;
    bool av_ok[4]; size_t arow[4];
    #pragma unroll
    for (int i = 0; i < 4; i++) {
        int gr = tile*128 + rb + 32*i;
        av_ok[i] = gr < cnt_e;
        arow[i] = (size_t)(base_e + gr) * I_DIM;
    }

    int lane = tid & 63, w = tid >> 6;
    int wm = w >> 1, wn = w & 1;
    int l16 = lane & 15, quad = lane >> 4;

    f32x4 acc[4][4];
    #pragma unroll
    for (int a = 0; a < 4; a++)
        #pragma unroll
        for (int b = 0; b < 4; b++) acc[a][b] = (f32x4){0.f, 0.f, 0.f, 0.f};

    const bf16x8 zero8 = {0,0,0,0,0,0,0,0};
    for (int k0 = 0; k0 < I_DIM; k0 += 64) {
        #pragma unroll
        for (int i = 0; i < 4; i++) {
            int r = rb + 32*i;
            bf16x8 av = zero8;
            if (av_ok[i]) av = *(const bf16x8*)(hbuf + arow[i] + k0 + c8);
            *(bf16x8*)&As[r][c8] = av;
            int n = bn*128 + r;
            *(bf16x8*)&Bs[r][c8] = *(const bf16x8*)(Wd_e + (size_t)n*I_DIM + k0 + c8);
        }
        __syncthreads();
        #pragma unroll
        for (int ks = 0; ks < 2; ks++) {
            bf16x8 af[4], bb[4];
            #pragma unroll
            for (int mt = 0; mt < 4; mt++)
                af[mt] = *(const bf16x8*)&As[wm*64 + mt*16 + l16][ks*32 + quad*8];
            #pragma unroll
            for (int nt = 0; nt < 4; nt++)
                bb[nt] = *(const bf16x8*)&Bs[wn*64 + nt*16 + l16][ks*32 + quad*8];
            #pragma unroll
            for (int mt = 0; mt < 4; mt++)
                #pragma unroll
                for (int nt = 0; nt < 4; nt++)
                    acc[mt][nt] = __builtin_amdgcn_mfma_f32_16x16x32_bf16(af[mt], bb[nt], acc[mt][nt], 0, 0, 0);
        }
        __syncthreads();
    }

    #pragma unroll
    for (int mt = 0; mt < 4; mt++) {
        #pragma unroll
        for (int r = 0; r < 4; r++) {
            int row = wm*64 + mt*16 + quad*4 + r;
            if (row < cnt_local) {
                int gr = tile*128 + row;
                int token = rows_e[gr];
                float wt = wts_e[gr];
                float* op = out + (size_t)token * H_DIM + bn*128 + wn*64;
                #pragma unroll
                for (int nt = 0; nt < 4; nt++)
                    atomicAdd(op + nt*16 + l16, wt * acc[mt][nt][r]);
            }
        }
    }
}

// ---------------- launch ----------------
extern "C" void kernel_launch(void* const* d_in, const int* in_sizes, int n_in,
                              void* d_out, int out_size, void* d_ws, size_t ws_size,
                              hipStream_t stream) {
    const float* x   = (const float*)d_in[0];
    const float* wg  = (const float*)d_in[1];
    const float* wgp = (const float*)d_in[2];
    const float* wup = (const float*)d_in[3];
    const float* wdp = (const float*)d_in[4];
    float* out = (float*)d_out;
    char* ws = (char*)d_ws;

    __hip_bfloat16* xb   = (__hip_bfloat16*)(ws + XB_OFF);
    __hip_bfloat16* Wgt  = (__hip_bfloat16*)(ws + WGT_OFF);
    __hip_bfloat16* Wut  = (__hip_bfloat16*)(ws + WUT_OFF);
    __hip_bfloat16* Wdt  = (__hip_bfloat16*)(ws + WDT_OFF);
    __hip_bfloat16* hbuf = (__hip_bfloat16*)(ws + HB_OFF);
    int*   rowsp  = (int*)(ws + ROWS_OFF);
    float* wtsp   = (float*)(ws + WTS_OFF);
    int*   cntp   = (int*)(ws + CNT_OFF);
    int*   basep  = (int*)(ws + BASE_OFF);
    int*   tilesp = (int*)(ws + TILES_OFF);
    int*   ntp    = (int*)(ws + NT_OFF);

    hipMemsetAsync(cntp, 0, 256, stream);
    hipMemsetAsync(out, 0, (size_t)out_size * sizeof(float), stream);

    convert_x_kernel<<<(T_TOK * H_DIM) / 1024, 256, 0, stream>>>(x, xb);
    transpose_convert_kernel<<<dim3(I_DIM/32, H_DIM/32, E_NUM), dim3(32, 8), 0, stream>>>(wgp, Wgt, H_DIM, I_DIM);
    transpose_convert_kernel<<<dim3(I_DIM/32, H_DIM/32, E_NUM), dim3(32, 8), 0, stream>>>(wup, Wut, H_DIM, I_DIM);
    transpose_convert_kernel<<<dim3(H_DIM/32, I_DIM/32, E_NUM), dim3(32, 8), 0, stream>>>(wdp, Wdt, I_DIM, H_DIM);
    router_kernel<<<T_TOK, 64, 0, stream>>>(x, wg, cntp, rowsp, wtsp);
    schedule_kernel<<<1, 1, 0, stream>>>(cntp, basep, tilesp, ntp);
    gemm_gateup_kernel<<<dim3(I_DIM/128, MAX_TILES), 256, 0, stream>>>(
        xb, Wgt, Wut, hbuf, rowsp, cntp, basep, tilesp, ntp);
    gemm_down_kernel<<<dim3(H_DIM/128, MAX_TILES), 256, 0, stream>>>(
        hbuf, Wdt, out, rowsp, wtsp, cntp, basep, tilesp, ntp);
}

// Round 2
// 1967.129 us; speedup vs baseline: 1.1501x; 1.1501x over previous
//
#include <hip/hip_runtime.h>
#include <hip/hip_bf16.h>
#include <math.h>

#define T_TOK 16384
#define H_DIM 1024
#define I_DIM 2048
#define E_NUM 16
#define MAX_TILES 272   // sum_e ceil(cnt_e/128) <= (32768 + 16*127)/128 < 272

typedef short bf16x8 __attribute__((ext_vector_type(8)));
typedef float f32x4 __attribute__((ext_vector_type(4)));

// ---------------- workspace layout (bytes) ----------------
static constexpr size_t XB_BYTES  = (size_t)T_TOK * H_DIM * 2;           // 32 MB
static constexpr size_t W_BYTES   = (size_t)E_NUM * H_DIM * I_DIM * 2;   // 64 MB
static constexpr size_t HB_BYTES  = (size_t)2 * T_TOK * I_DIM * 2;       // 128 MB
static constexpr size_t LIST_BYTES= (size_t)E_NUM * T_TOK * 4;           // 1 MB

static constexpr size_t XB_OFF    = 0;
static constexpr size_t WGT_OFF   = XB_OFF + XB_BYTES;
static constexpr size_t WUT_OFF   = WGT_OFF + W_BYTES;
static constexpr size_t WDT_OFF   = WUT_OFF + W_BYTES;
static constexpr size_t HB_OFF    = WDT_OFF + W_BYTES;
static constexpr size_t ROWS_OFF  = HB_OFF + HB_BYTES;
static constexpr size_t WTS_OFF   = ROWS_OFF + LIST_BYTES;
static constexpr size_t CNT_OFF   = WTS_OFF + LIST_BYTES;
static constexpr size_t BASE_OFF  = CNT_OFF + 256;
static constexpr size_t TILES_OFF = BASE_OFF + 256;
static constexpr size_t NT_OFF    = TILES_OFF + 2048;

// ---------------- async global->LDS 16B helper ----------------
__device__ __forceinline__ void async_ld16(void* lds, const void* g) {
    __builtin_amdgcn_global_load_lds(
        (const __attribute__((address_space(1))) void*)g,
        (__attribute__((address_space(3))) void*)lds,
        16, 0, 0);
}

// ---------------- fp32 -> bf16 straight convert (x) ----------------
__global__ void convert_x_kernel(const float* __restrict__ x, __hip_bfloat16* __restrict__ xb) {
    int i = (blockIdx.x * 256 + threadIdx.x) * 4;
    const float4 v = *(const float4*)(x + i);
    union { __hip_bfloat16 h[4]; ushort4 u; } cv;
    cv.h[0] = __float2bfloat16(v.x);
    cv.h[1] = __float2bfloat16(v.y);
    cv.h[2] = __float2bfloat16(v.z);
    cv.h[3] = __float2bfloat16(v.w);
    *(ushort4*)(xb + i) = cv.u;
}

// in: [E][R][C] fp32  ->  out: [E][C][R] bf16   (B^T layout for MFMA frag reads)
__global__ void transpose_convert_kernel(const float* __restrict__ in,
                                         __hip_bfloat16* __restrict__ out,
                                         int R, int C) {
    __shared__ float tile[32][33];
    int e = blockIdx.z;
    int c0 = blockIdx.x * 32;
    int r0 = blockIdx.y * 32;
    const float* pin = in + (size_t)e * R * C;
    __hip_bfloat16* pout = out + (size_t)e * R * C;
    int tx = threadIdx.x, ty = threadIdx.y;   // block (32,8)
    #pragma unroll
    for (int j = 0; j < 4; j++)
        tile[ty + j*8][tx] = pin[(size_t)(r0 + ty + j*8) * C + (c0 + tx)];
    __syncthreads();
    #pragma unroll
    for (int j = 0; j < 4; j++)
        pout[(size_t)(c0 + ty + j*8) * R + (r0 + tx)] = __float2bfloat16(tile[tx][ty + j*8]);
}

// ---------------- router: fp64 logits, top-2, renorm, atomic list build ----------------
__global__ void router_kernel(const float* __restrict__ x, const float* __restrict__ wg,
                              int* __restrict__ cnt, int* __restrict__ rows,
                              float* __restrict__ wts) {
    int t = blockIdx.x;
    int lane = threadIdx.x;   // 64 threads = 1 wave
    float xv[16];
    const float* xp = x + (size_t)t * H_DIM;
    #pragma unroll
    for (int j = 0; j < 16; j++) xv[j] = xp[j*64 + lane];
    double logits[E_NUM];
    #pragma unroll
    for (int e = 0; e < E_NUM; e++) {
        double p = 0.0;
        #pragma unroll
        for (int j = 0; j < 16; j++)
            p += (double)xv[j] * (double)wg[(j*64 + lane) * E_NUM + e];
        #pragma unroll
        for (int off = 32; off > 0; off >>= 1) p += __shfl_down(p, off);
        logits[e] = p;
    }
    if (lane == 0) {
        int i1 = 0; double v1 = logits[0];
        #pragma unroll
        for (int e = 1; e < E_NUM; e++) if (logits[e] > v1) { v1 = logits[e]; i1 = e; }
        int i2 = -1; double v2 = -1e300;
        #pragma unroll
        for (int e = 0; e < E_NUM; e++) if (e != i1 && logits[e] > v2) { v2 = logits[e]; i2 = e; }
        double w1 = 1.0 / (1.0 + exp(v2 - v1));
        float w1f = (float)w1, w2f = (float)(1.0 - w1);
        int s1 = atomicAdd(&cnt[i1], 1);
        rows[i1 * T_TOK + s1] = t; wts[i1 * T_TOK + s1] = w1f;
        int s2 = atomicAdd(&cnt[i2], 1);
        rows[i2 * T_TOK + s2] = t; wts[i2 * T_TOK + s2] = w2f;
    }
}

// ---------------- schedule: exclusive scan + tile descriptors ----------------
__global__ void schedule_kernel(const int* __restrict__ cnt, int* __restrict__ base,
                                int* __restrict__ tiles, int* __restrict__ ntiles) {
    int b = 0, nt = 0;
    for (int e = 0; e < E_NUM; e++) {
        base[e] = b;
        int c = cnt[e];
        int m = (c + 127) >> 7;
        for (int i = 0; i < m; i++) tiles[nt++] = (e << 16) | i;
        b += c;
    }
    ntiles[0] = nt;
}

// ---------------- unified grouped-GEMM template ----------------
// MODE 0: gate   — A = xb (token gather), C: hbuf[row] = g (bf16)
// MODE 1: up     — A = xb (token gather), C: hbuf[row] = acc * silu(hbuf[row]) in-place
// MODE 2: down   — A = hbuf (contiguous),  C: atomicAdd(out[token], wt*acc)
// B layout: [E][N][K] bf16. LDS chunk-major [8][128][8] for conflict-free ds_read_b128
// and global_load_lds wave-uniform-base staging.
template<int MODE>
__global__ __launch_bounds__(256) void moe_gemm_kernel(
    const __hip_bfloat16* __restrict__ Abase,
    const __hip_bfloat16* __restrict__ Bw,
    void* __restrict__ Cout,
    const int* __restrict__ rows, const float* __restrict__ wts,
    const int* __restrict__ cnt, const int* __restrict__ base,
    const int* __restrict__ tiles, const int* __restrict__ ntiles,
    int Kd, int Nd)
{
    if ((int)blockIdx.y >= ntiles[0]) return;
    int td = tiles[blockIdx.y];
    int e = td >> 16, tile = td & 0xffff;
    int cnt_e = cnt[e], base_e = base[e];
    int cnt_local = cnt_e - tile * 128;
    int bn = blockIdx.x;
    const int* rows_e = rows + e * T_TOK;
    const __hip_bfloat16* Be = Bw + (size_t)e * Nd * Kd;

    __shared__ __align__(16) __hip_bfloat16 As[8][128][8];
    __shared__ __align__(16) __hip_bfloat16 Bs[8][128][8];

    int tid = threadIdx.x;
    int w = tid >> 6, lane = tid & 63;

    // staging slots: unit u = w*4+j covers LDS bytes [u*1024, u*1024+1024)
    // = chunk (u>>1), rows (u&1)*64 + lane, HW writes lane*16 past base
    const __hip_bfloat16* aptr[4];
    const __hip_bfloat16* bptr[4];
    uint32_t loff[4];
    #pragma unroll
    for (int j = 0; j < 4; j++) {
        int u = w * 4 + j;
        int chunk = u >> 1, half = u & 1;
        int r = half * 64 + lane;
        int gr = tile * 128 + r;
        size_t arow;
        if (MODE == 2) {
            int rr = base_e + gr;
            if (rr > 2 * T_TOK - 1) rr = 2 * T_TOK - 1;
            arow = (size_t)rr;
        } else {
            arow = (size_t)((gr < cnt_e) ? rows_e[gr] : 0);
        }
        aptr[j] = Abase + arow * Kd + chunk * 8;
        bptr[j] = Be + (size_t)(bn * 128 + r) * Kd + chunk * 8;
        loff[j] = (uint32_t)(u * 1024);
    }

    int wm = w >> 1, wn = w & 1;
    int l16 = lane & 15, quad = lane >> 4;

    f32x4 acc[4][4];
    #pragma unroll
    for (int a = 0; a < 4; a++)
        #pragma unroll
        for (int b = 0; b < 4; b++) acc[a][b] = (f32x4){0.f, 0.f, 0.f, 0.f};

    char* AsB = (char*)&As[0][0][0];
    char* BsB = (char*)&Bs[0][0][0];

    for (int k0 = 0; k0 < Kd; k0 += 64) {
        #pragma unroll
        for (int j = 0; j < 4; j++) {
            async_ld16(AsB + loff[j], aptr[j]);
            async_ld16(BsB + loff[j], bptr[j]);
            aptr[j] += 64; bptr[j] += 64;
        }
        __syncthreads();
        #pragma unroll
        for (int ks = 0; ks < 2; ks++) {
            bf16x8 af[4], bfr[4];
            #pragma unroll
            for (int mt = 0; mt < 4; mt++)
                af[mt] = *(const bf16x8*)&As[ks*4 + quad][wm*64 + mt*16 + l16][0];
            #pragma unroll
            for (int nt = 0; nt < 4; nt++)
                bfr[nt] = *(const bf16x8*)&Bs[ks*4 + quad][wn*64 + nt*16 + l16][0];
            #pragma unroll
            for (int mt = 0; mt < 4; mt++)
                #pragma unroll
                for (int nt = 0; nt < 4; nt++)
                    acc[mt][nt] = __builtin_amdgcn_mfma_f32_16x16x32_bf16(af[mt], bfr[nt], acc[mt][nt], 0, 0, 0);
        }
        __syncthreads();
    }

    // epilogue: C/D layout col=lane&15, row=quad*4+r (m89-verified)
    #pragma unroll
    for (int mt = 0; mt < 4; mt++) {
        #pragma unroll
        for (int r = 0; r < 4; r++) {
            int row = wm*64 + mt*16 + quad*4 + r;
            if (row < cnt_local) {
                int gr = tile * 128 + row;
                if (MODE == 0) {
                    __hip_bfloat16* hp = (__hip_bfloat16*)Cout + (size_t)(base_e + gr) * Nd;
                    #pragma unroll
                    for (int nt = 0; nt < 4; nt++) {
                        int col = bn*128 + wn*64 + nt*16 + l16;
                        hp[col] = __float2bfloat16(acc[mt][nt][r]);
                    }
                } else if (MODE == 1) {
                    __hip_bfloat16* hp = (__hip_bfloat16*)Cout + (size_t)(base_e + gr) * Nd;
                    #pragma unroll
                    for (int nt = 0; nt < 4; nt++) {
                        int col = bn*128 + wn*64 + nt*16 + l16;
                        float g = __bfloat162float(hp[col]);
                        float u = acc[mt][nt][r];
                        hp[col] = __float2bfloat16(u * (g / (1.f + expf(-g))));
                    }
                } else {
                    int token = rows_e[gr];
                    float wt = (wts + e * T_TOK)[gr];
                    float* op = (float*)Cout + (size_t)token * H_DIM + bn*128 + wn*64;
                    #pragma unroll
                    for (int nt = 0; nt < 4; nt++)
                        atomicAdd(op + nt*16 + l16, wt * acc[mt][nt][r]);
                }
            }
        }
    }
}

// ---------------- launch ----------------
extern "C" void kernel_launch(void* const* d_in, const int* in_sizes, int n_in,
                              void* d_out, int out_size, void* d_ws, size_t ws_size,
                              hipStream_t stream) {
    const float* x   = (const float*)d_in[0];
    const float* wg  = (const float*)d_in[1];
    const float* wgp = (const float*)d_in[2];
    const float* wup = (const float*)d_in[3];
    const float* wdp = (const float*)d_in[4];
    float* out = (float*)d_out;
    char* ws = (char*)d_ws;

    __hip_bfloat16* xb   = (__hip_bfloat16*)(ws + XB_OFF);
    __hip_bfloat16* Wgt  = (__hip_bfloat16*)(ws + WGT_OFF);
    __hip_bfloat16* Wut  = (__hip_bfloat16*)(ws + WUT_OFF);
    __hip_bfloat16* Wdt  = (__hip_bfloat16*)(ws + WDT_OFF);
    __hip_bfloat16* hbuf = (__hip_bfloat16*)(ws + HB_OFF);
    int*   rowsp  = (int*)(ws + ROWS_OFF);
    float* wtsp   = (float*)(ws + WTS_OFF);
    int*   cntp   = (int*)(ws + CNT_OFF);
    int*   basep  = (int*)(ws + BASE_OFF);
    int*   tilesp = (int*)(ws + TILES_OFF);
    int*   ntp    = (int*)(ws + NT_OFF);

    hipMemsetAsync(cntp, 0, 256, stream);
    hipMemsetAsync(out, 0, (size_t)out_size * sizeof(float), stream);

    convert_x_kernel<<<(T_TOK * H_DIM) / 1024, 256, 0, stream>>>(x, xb);
    transpose_convert_kernel<<<dim3(I_DIM/32, H_DIM/32, E_NUM), dim3(32, 8), 0, stream>>>(wgp, Wgt, H_DIM, I_DIM);
    transpose_convert_kernel<<<dim3(I_DIM/32, H_DIM/32, E_NUM), dim3(32, 8), 0, stream>>>(wup, Wut, H_DIM, I_DIM);
    transpose_convert_kernel<<<dim3(H_DIM/32, I_DIM/32, E_NUM), dim3(32, 8), 0, stream>>>(wdp, Wdt, I_DIM, H_DIM);
    router_kernel<<<T_TOK, 64, 0, stream>>>(x, wg, cntp, rowsp, wtsp);
    schedule_kernel<<<1, 1, 0, stream>>>(cntp, basep, tilesp, ntp);

    // gate: g -> hbuf
    moe_gemm_kernel<0><<<dim3(I_DIM/128, MAX_TILES), 256, 0, stream>>>(
        xb, Wgt, hbuf, rowsp, wtsp, cntp, basep, tilesp, ntp, H_DIM, I_DIM);
    // up + silu-combine in place: hbuf = u * silu(g)
    moe_gemm_kernel<1><<<dim3(I_DIM/128, MAX_TILES), 256, 0, stream>>>(
        xb, Wut, hbuf, rowsp, wtsp, cntp, basep, tilesp, ntp, H_DIM, I_DIM);
    // down + weighted scatter
    moe_gemm_kernel<2><<<dim3(H_DIM/128, MAX_TILES), 256, 0, stream>>>(
        hbuf, Wdt, out, rowsp, wtsp, cntp, basep, tilesp, ntp, I_DIM, H_DIM);
}